// Round 15
// baseline (940.124 us; speedup 1.0000x reference)
//
#include <hip/hip_runtime.h>
#include <math.h>

// decoderRNN: attention LSTM caption decoder, teacher-forced.
// B=64 L=49 F=2048 T=32 V=15000 E=H=A=512
#define B_ 64
#define L_ 49
#define F_DIM 2048
#define T_ 32
#define V_ 15000
#define E_ 512
#define H_ 512
#define A_ 512

typedef __attribute__((ext_vector_type(8))) short s16x8;
typedef __attribute__((ext_vector_type(4))) short s16x4;
typedef __attribute__((ext_vector_type(4))) float f32x4;

__device__ __forceinline__ unsigned short f2b(float x) {
    union { float f; unsigned int u; } v; v.f = x;
    unsigned int r = v.u + 0x7FFF + ((v.u >> 16) & 1);
    return (unsigned short)(r >> 16);
}
__device__ __forceinline__ float b2f(unsigned short u) {
    union { unsigned int i; float f; } v; v.i = ((unsigned int)u) << 16; return v.f;
}
__device__ __forceinline__ float rcp_fast(float x) {
    return __builtin_amdgcn_rcpf(x);
}
__device__ __forceinline__ float tanhf_fast(float x) {
    x = fminf(fmaxf(x, -15.f), 15.f);
    const float e = __expf(2.f * x);
    return (e - 1.f) * rcp_fast(e + 1.f);
}
__device__ __forceinline__ float sigmoid_fast(float x) {
    return rcp_fast(1.f + __expf(-x));
}

// ---- agent-scope coherent access (LLC, bypass non-coherent per-XCD L2) ----
__device__ __forceinline__ float aload_f(const float* p) {
    return __hip_atomic_load((const float*)p, __ATOMIC_RELAXED, __HIP_MEMORY_SCOPE_AGENT);
}
__device__ __forceinline__ void astore_f(float* p, float v) {
    __hip_atomic_store(p, v, __ATOMIC_RELAXED, __HIP_MEMORY_SCOPE_AGENT);
}
__device__ __forceinline__ unsigned long long aload_u64(const void* p) {
    return __hip_atomic_load((const unsigned long long*)p, __ATOMIC_RELAXED, __HIP_MEMORY_SCOPE_AGENT);
}
__device__ __forceinline__ void astore_u32(void* p, unsigned v) {
    __hip_atomic_store((unsigned*)p, v, __ATOMIC_RELAXED, __HIP_MEMORY_SCOPE_AGENT);
}
__device__ __forceinline__ unsigned apoll(const unsigned* p) {
    return __hip_atomic_load(p, __ATOMIC_RELAXED, __HIP_MEMORY_SCOPE_AGENT);
}
__device__ __forceinline__ void aset(unsigned* p, unsigned v) {
    __hip_atomic_store(p, v, __ATOMIC_RELAXED, __HIP_MEMORY_SCOPE_AGENT);
}

// ---------------- fused bf16 cast: feat | [W_a;W_ihF] | fc_W ----------------
__global__ __launch_bounds__(256)
void k_castall(const float* __restrict__ feat, const float* __restrict__ W_a,
               const float* __restrict__ W_ih, const float* __restrict__ fc_W,
               unsigned short* __restrict__ feat_bf,
               unsigned short* __restrict__ wcomb_bf,
               unsigned short* __restrict__ fcW_bf)
{
    const int r  = blockIdx.y;
    const int c4 = blockIdx.x * 256 + threadIdx.x;
    const float* src;
    unsigned short* dst;
    int cols;
    if (r < 3136)      { src = feat + (size_t)r * 2048;                 dst = feat_bf + (size_t)r * 2048;            cols = 2048; }
    else if (r < 3648) { const int rr = r - 3136; src = W_a + (size_t)rr * 2048;              dst = wcomb_bf + (size_t)rr * 2048;          cols = 2048; }
    else if (r < 5696) { const int rr = r - 3648; src = W_ih + (size_t)rr * 2560 + 512;       dst = wcomb_bf + (size_t)(rr + 512) * 2048;  cols = 2048; }
    else               { const int rr = r - 5696; src = fc_W + (size_t)rr * 512;              dst = fcW_bf + (size_t)rr * 512;             cols = 512; }
    if (c4 * 4 >= cols) return;
    float4 v = *reinterpret_cast<const float4*>(src + c4 * 4);
    ushort4 o;
    o.x = f2b(v.x); o.y = f2b(v.y); o.z = f2b(v.z); o.w = f2b(v.w);
    *reinterpret_cast<ushort4*>(dst + c4 * 4) = o;
}

// ---------------- U_a transpose-cast: UT[k][a] = bf16(U[a][k]) ----------------
__global__ __launch_bounds__(256)
void k_castT(const float* __restrict__ U, unsigned short* __restrict__ UT)
{
    __shared__ float tile[64][65];
    const int a0 = blockIdx.x * 64;
    const int k0 = blockIdx.y * 64;
    const int c  = threadIdx.x & 63;
    const int r0 = threadIdx.x >> 6;     // 0..3
    #pragma unroll
    for (int rr = 0; rr < 16; ++rr) {
        const int r = r0 * 16 + rr;
        tile[r][c] = U[(size_t)(a0 + r) * 512 + k0 + c];
    }
    __syncthreads();
    #pragma unroll
    for (int rr = 0; rr < 16; ++rr) {
        const int r = r0 * 16 + rr;      // k offset
        UT[(size_t)(k0 + r) * 512 + a0 + c] = f2b(tile[c][r]);
    }
}

// ---- bf16 MFMA GEMM: C[M,N] = A[M,K] @ W^T ----
// W rows [0,N0) from W0, [N0,N) from W1; w32!=0 -> W is f32 (cvt during stage).
// bias0 added for n<N0; bias1 added for all n.
// permT!=0: row = (m&63)*permT + (m>>6). obf!=0: store bf16.
#define LDSW 40
__global__ __launch_bounds__(256)
void gemm_mfma(const unsigned short* __restrict__ A, int lda,
               const void* __restrict__ W0p, int ldw0, int N0,
               const void* __restrict__ W1p, int ldw1, int w32,
               const float* __restrict__ bias0, const float* __restrict__ bias1,
               float* __restrict__ C, int ldc,
               int M, int N, int K, int permT, int obf)
{
    __shared__ unsigned short As[128 * LDSW];
    __shared__ unsigned short Ws[128 * LDSW];

    const int tid  = threadIdx.x;
    const int m0   = blockIdx.x * 128;
    const int n0   = blockIdx.y * 128;
    const int wave = tid >> 6;
    const int lane = tid & 63;
    const int wr   = (wave >> 1) * 64;
    const int wc   = (wave & 1) * 64;

    f32x4 acc[4][4];
    #pragma unroll
    for (int i = 0; i < 4; ++i)
        #pragma unroll
        for (int j = 0; j < 4; ++j)
            acc[i][j] = (f32x4)(0.f);

    const int fr = lane & 15;
    const int fk = (lane >> 4) * 8;

    for (int kc = 0; kc < K; kc += 32) {
        ushort4 av[2][2], wv[2][2];
        #pragma unroll
        for (int i = 0; i < 2; ++i) {
            const int idx = tid + i * 256;
            const int row = idx >> 2;
            const int seg = idx & 3;
            av[i][0] = make_ushort4(0, 0, 0, 0); av[i][1] = make_ushort4(0, 0, 0, 0);
            wv[i][0] = make_ushort4(0, 0, 0, 0); wv[i][1] = make_ushort4(0, 0, 0, 0);
            if (m0 + row < M) {
                const float4 t0 = *reinterpret_cast<const float4*>(
                    A + (size_t)(m0 + row) * lda + kc + seg * 8);
                *reinterpret_cast<float4*>(&av[i][0]) = t0;
            }
            const int n_abs = n0 + row;
            if (n_abs < N) {
                if (w32) {
                    const float* wrow = (n_abs < N0)
                        ? ((const float*)W0p + (size_t)n_abs * ldw0)
                        : ((const float*)W1p + (size_t)(n_abs - N0) * ldw1);
                    const float4 x = *reinterpret_cast<const float4*>(wrow + kc + seg * 8);
                    const float4 y = *reinterpret_cast<const float4*>(wrow + kc + seg * 8 + 4);
                    wv[i][0] = make_ushort4(f2b(x.x), f2b(x.y), f2b(x.z), f2b(x.w));
                    wv[i][1] = make_ushort4(f2b(y.x), f2b(y.y), f2b(y.z), f2b(y.w));
                } else {
                    const unsigned short* wrow = (n_abs < N0)
                        ? ((const unsigned short*)W0p + (size_t)n_abs * ldw0)
                        : ((const unsigned short*)W1p + (size_t)(n_abs - N0) * ldw1);
                    const float4 t0 = *reinterpret_cast<const float4*>(wrow + kc + seg * 8);
                    *reinterpret_cast<float4*>(&wv[i][0]) = t0;
                }
            }
        }
        __syncthreads();
        #pragma unroll
        for (int i = 0; i < 2; ++i) {
            const int idx = tid + i * 256;
            const int row = idx >> 2;
            const int seg = idx & 3;
            *reinterpret_cast<ushort4*>(&As[row * LDSW + seg * 8])     = av[i][0];
            *reinterpret_cast<ushort4*>(&As[row * LDSW + seg * 8 + 4]) = av[i][1];
            *reinterpret_cast<ushort4*>(&Ws[row * LDSW + seg * 8])     = wv[i][0];
            *reinterpret_cast<ushort4*>(&Ws[row * LDSW + seg * 8 + 4]) = wv[i][1];
        }
        __syncthreads();

        s16x8 afr[4], bfr[4];
        #pragma unroll
        for (int mf = 0; mf < 4; ++mf)
            afr[mf] = *reinterpret_cast<const s16x8*>(&As[(wr + mf * 16 + fr) * LDSW + fk]);
        #pragma unroll
        for (int nf = 0; nf < 4; ++nf)
            bfr[nf] = *reinterpret_cast<const s16x8*>(&Ws[(wc + nf * 16 + fr) * LDSW + fk]);

        #pragma unroll
        for (int mf = 0; mf < 4; ++mf)
            #pragma unroll
            for (int nf = 0; nf < 4; ++nf)
                acc[mf][nf] = __builtin_amdgcn_mfma_f32_16x16x32_bf16(
                    afr[mf], bfr[nf], acc[mf][nf], 0, 0, 0);
    }

    const int cr = (lane >> 4) * 4;
    const int cc = lane & 15;
    #pragma unroll
    for (int nf = 0; nf < 4; ++nf) {
        const int n = n0 + wc + nf * 16 + cc;
        if (n >= N) continue;
        float bv = 0.f;
        if (bias0 && n < N0) bv += bias0[n];
        if (bias1) bv += bias1[n];
        #pragma unroll
        for (int mf = 0; mf < 4; ++mf) {
            #pragma unroll
            for (int r = 0; r < 4; ++r) {
                const int m = m0 + wr + mf * 16 + cr + r;
                if (m >= M) continue;
                const size_t row = permT ? ((size_t)(m & 63) * permT + (size_t)(m >> 6))
                                         : (size_t)m;
                const float v = acc[mf][nf][r] + bv;
                if (obf) ((unsigned short*)C)[row * (size_t)ldc + n] = f2b(v);
                else     C[row * (size_t)ldc + n] = v;
            }
        }
    }
}

// ---------------- generic tiled f32 GEMM (tiny prologue matmuls) ----------------
// obf: 0=f32->C ; 1=bf16->C ; 2=split (n<N0 bf16->C ld N0, n>=N0 f32->C2 ld N-N0)
__global__ __launch_bounds__(256)
void gemm64(const float* __restrict__ A, int lda,
            const float* __restrict__ W0, int ldw0, int N0,
            const float* __restrict__ W1, int ldw1,
            const float* __restrict__ bias0, const float* __restrict__ bias1,
            float* __restrict__ C, int ldc,
            int N, int K, int obf, float* __restrict__ C2)
{
    __shared__ float As[16][64];
    __shared__ float Ws[16][64];

    const int tid = threadIdx.x;
    const int m0  = blockIdx.x * 64;
    const int n0  = blockIdx.y * 64;

    const int lr = tid >> 2;
    const int kq = tid & 3;

    const int n_abs = n0 + lr;
    const bool wvalid = (n_abs < N);
    const float* wrow = nullptr;
    if (wvalid)
        wrow = (n_abs < N0) ? (W0 + (size_t)n_abs * ldw0)
                            : (W1 + (size_t)(n_abs - N0) * ldw1);
    const float* arow = A + (size_t)(m0 + lr) * lda;

    const int ty = tid >> 4;
    const int tx = tid & 15;

    float acc[4][4] = {{0.f}};

    for (int kc = 0; kc < K; kc += 16) {
        float4 av = *reinterpret_cast<const float4*>(arow + kc + kq * 4);
        float4 wv = make_float4(0.f, 0.f, 0.f, 0.f);
        if (wvalid)
            wv = *reinterpret_cast<const float4*>(wrow + kc + kq * 4);

        __syncthreads();
        As[kq * 4 + 0][lr] = av.x;
        As[kq * 4 + 1][lr] = av.y;
        As[kq * 4 + 2][lr] = av.z;
        As[kq * 4 + 3][lr] = av.w;
        Ws[kq * 4 + 0][lr] = wv.x;
        Ws[kq * 4 + 1][lr] = wv.y;
        Ws[kq * 4 + 2][lr] = wv.z;
        Ws[kq * 4 + 3][lr] = wv.w;
        __syncthreads();

        #pragma unroll
        for (int kk = 0; kk < 16; ++kk) {
            const float4 a4 = *reinterpret_cast<const float4*>(&As[kk][ty * 4]);
            const float4 w4 = *reinterpret_cast<const float4*>(&Ws[kk][tx * 4]);
            const float aa[4] = {a4.x, a4.y, a4.z, a4.w};
            const float ww[4] = {w4.x, w4.y, w4.z, w4.w};
            #pragma unroll
            for (int i = 0; i < 4; ++i)
                #pragma unroll
                for (int j = 0; j < 4; ++j)
                    acc[i][j] = fmaf(aa[i], ww[j], acc[i][j]);
        }
    }

    #pragma unroll
    for (int i = 0; i < 4; ++i) {
        const int m = m0 + ty * 4 + i;
        #pragma unroll
        for (int j = 0; j < 4; ++j) {
            const int n = n0 + tx * 4 + j;
            if (n >= N) continue;
            float v = acc[i][j];
            if (bias0 && n < N0) v += bias0[n];
            if (bias1 && n >= N0) v += bias1[n - N0];
            if (obf == 2) {
                if (n < N0) ((unsigned short*)C)[(size_t)m * N0 + n] = f2b(v);
                else        C2[(size_t)m * (N - N0) + (n - N0)] = v;
            } else if (obf == 1) {
                ((unsigned short*)C)[(size_t)m * ldc + n] = f2b(v);
            } else {
                C[(size_t)m * ldc + n] = v;
            }
        }
    }
}

// ---------------- mean over L (f32 out, feeds gemm64) ----------------
__global__ __launch_bounds__(256)
void k_mean(const float* __restrict__ feat, float* __restrict__ mean_f)
{
    const int idx = blockIdx.x * 256 + threadIdx.x;
    const int b = idx >> 11;
    const int f = idx & 2047;
    const float* p = feat + (size_t)b * L_ * F_DIM + f;
    float s = 0.f;
    #pragma unroll 7
    for (int l = 0; l < L_; ++l) s += p[(size_t)l * F_DIM];
    mean_f[idx] = s * (1.0f / 49.0f);
}

// ---------------- embedding gather (bf16 out) ----------------
__global__ __launch_bounds__(256)
void k_embgather(const float* __restrict__ table, const int* __restrict__ caps,
                 unsigned short* __restrict__ emb_bf)
{
    const int idx = blockIdx.x * 256 + threadIdx.x;
    const int e   = idx & 511;
    const int row = idx >> 9;
    const int t   = row >> 6;
    const int b   = row & 63;
    const int tok = caps[b * T_ + t];
    emb_bf[idx] = f2b(table[(size_t)tok * E_ + e]);
}

// ---------------- persistent recurrence kernel v9: 64 blocks, 2 events ----------------
// Block g == batch b. LDS holds 32 rows of W_hh (gate cols g*32..+31).
// The U_a (att2) part is computed LOCALLY per block from its OWN h by
// streaming transposed-bf16 U_a from L2 — this + scores + softmax runs at
// loop top BEFORE the h-ready wait (own h is block-local), taking the whole
// attention-score path off the cross-block critical chain.
// Per step, TWO events (proven drain->slot-store / wave-poll idiom):
//   ev1 h-ready (64 slotB)  -> stage all-h -> MFMA gate cols -> signal slotA
//   ev2 gate-cols-ready (64 slotA) -> gates + LSTM -> signal slotB
#define NBLK_RECUR 64u
// bar (uints, 16-uint padded): [i*16] slotB(i<64) ; [1024+i*16] slotA(i<64)

__global__ __launch_bounds__(512)
void k_recur(unsigned short* __restrict__ hbf,      // [64][512] bf16 (coherent)
             float* __restrict__ att2g,             // [64][2048] gate part (coherent)
             const unsigned short* __restrict__ uaT, // [512][512] bf16 U_a^T
             const float* __restrict__ W_hh,        // [2048][512]
             const float* __restrict__ U_a_b,       // [512]
             const unsigned short* __restrict__ attFb, // [3136][2560] bf16
             const float* __restrict__ g_emb,       // [32][64][2048]
             const float* __restrict__ v_w, const float* __restrict__ v_b,
             const float* __restrict__ c0,          // [64][512] initial c
             unsigned short* __restrict__ h_hist,   // [32][64][512] bf16
             unsigned* __restrict__ bar)
{
    const int g   = blockIdx.x;
    const int b   = g;
    const int tid = threadIdx.x;

    __shared__ unsigned short Wc[32 * 520];    // 32 W_hh rows (bf16)
    __shared__ unsigned short hsd[64 * 520];   // staged all-h (bf16, padded)
    __shared__ float red[4][512];              // att2 k-chunk partials
    __shared__ float a2[512];
    __shared__ float wl[64];
    __shared__ float gates[2048];
    __shared__ float hs[512];                  // own h (f32)
    __shared__ float vws[512];
    __shared__ float vub[512];

    const int wave = tid >> 6;
    const int lane = tid & 63;

    // one-time: 32 W_hh rows f32 -> bf16 LDS; v_w; U_a_b; own h0 -> hs
    for (int idx = tid; idx < 4096; idx += 512) {   // 32 rows x 128 float4
        const int r  = idx >> 7;
        const int kq = idx & 127;
        const float* src = W_hh + (size_t)(g * 32 + r) * 512;
        float4 v = *reinterpret_cast<const float4*>(src + kq * 4);
        unsigned short* d = &Wc[r * 520 + kq * 4];
        d[0] = f2b(v.x); d[1] = f2b(v.y); d[2] = f2b(v.z); d[3] = f2b(v.w);
    }
    vws[tid] = v_w[tid];
    vub[tid] = U_a_b[tid];
    hs[tid]  = b2f(hbf[b * 512 + tid]);
    const float vb0 = v_b[0];

    // per-thread constants
    const int ggrp = tid >> 7;          // gate group i/f/g/o
    const int jj   = (tid & 127) * 4;
    const int gc   = ggrp * 512 + jj;   // gate col [0,2048)
    float creg = c0[b * 512 + tid];

    // local-att2 decomposition: aq = output quad, kc = k-chunk
    const int aq = tid & 127;
    const int kc = tid >> 7;            // 0..3

    // phase-A constants
    const int tcol  = wave >> 2;        // 0/1: 16-col half of the 32 cols
    const int rows0 = (wave & 3) * 16;  // batch-row base
    const int frow  = lane & 15;
    const int fko   = (lane >> 4) * 8;
    __syncthreads();

    // step-invariant score-row prefetch (fixed-index, stays in VGPRs)
    s16x8 a1pf[7];
    #pragma unroll
    for (int i = 0; i < 7; ++i) {
        int l = wave + i * 8; if (l > 48) l = 48;   // clamped; unused if OOB
        a1pf[i] = *reinterpret_cast<const s16x8*>(
            attFb + (size_t)(b * L_ + l) * 2560 + lane * 8);
    }

    for (int t = 0; t < T_; ++t) {
        // ===== LOCAL (no wait): att2 = own-h @ U_a^T, scores, softmax =====
        {
            float p0 = 0.f, p1 = 0.f, p2 = 0.f, p3 = 0.f;
            const unsigned short* up = uaT + ((size_t)kc * 128) * 512 + aq * 4;
            #pragma unroll 4
            for (int k = 0; k < 128; ++k) {
                const float hk = hs[kc * 128 + k];
                const s16x4 u = *reinterpret_cast<const s16x4*>(up + (size_t)k * 512);
                p0 = fmaf(hk, b2f((unsigned short)u[0]), p0);
                p1 = fmaf(hk, b2f((unsigned short)u[1]), p1);
                p2 = fmaf(hk, b2f((unsigned short)u[2]), p2);
                p3 = fmaf(hk, b2f((unsigned short)u[3]), p3);
            }
            red[kc][aq * 4 + 0] = p0;
            red[kc][aq * 4 + 1] = p1;
            red[kc][aq * 4 + 2] = p2;
            red[kc][aq * 4 + 3] = p3;
        }
        __syncthreads();
        a2[tid] = red[0][tid] + red[1][tid] + red[2][tid] + red[3][tid] + vub[tid];
        __syncthreads();

        // scores over L=49 (fixed trip, compile-time a1pf index)
        #pragma unroll
        for (int i = 0; i < 7; ++i) {
            const int l = wave + i * 8;      // wave-uniform
            if (l < L_) {
                float s = 0.f;
                #pragma unroll
                for (int j = 0; j < 8; ++j)
                    s += tanhf_fast(b2f((unsigned short)a1pf[i][j]) + a2[lane * 8 + j]) * vws[lane * 8 + j];
                #pragma unroll
                for (int off = 32; off > 0; off >>= 1) s += __shfl_down(s, off);
                if (lane == 0) wl[l] = s + vb0;
            }
        }
        __syncthreads();

        if (tid < 64) {
            float v = (tid < L_) ? wl[tid] : -3.0e38f;
            float mx = v;
            #pragma unroll
            for (int off = 32; off > 0; off >>= 1) mx = fmaxf(mx, __shfl_xor(mx, off));
            float e = (tid < L_) ? __expf(v - mx) : 0.f;
            float sum = e;
            #pragma unroll
            for (int off = 32; off > 0; off >>= 1) sum += __shfl_xor(sum, off);
            if (tid < L_) wl[tid] = e * rcp_fast(sum);
        }
        // per-t g_emb prefetch (immutable)
        const float4 ge = *reinterpret_cast<const float4*>(
            g_emb + ((size_t)t * 64 + b) * 2048 + gc);

        // ===== ev1: h(t) ready for ALL batches =====
        if (t > 0) {
            if (tid < 64) {
                while (!__all((int)(apoll(bar + tid * 16) >= (unsigned)t)))
                    __builtin_amdgcn_s_sleep(1);
            }
        }
        __syncthreads();

        // ===== stage all-h -> LDS (bulk parallel agent loads) =====
        {
            unsigned long long v[16];
            #pragma unroll
            for (int k = 0; k < 16; ++k)
                v[k] = aload_u64((const unsigned char*)hbf + ((size_t)(tid + k * 512)) * 8);
            #pragma unroll
            for (int k = 0; k < 16; ++k) {
                const int s   = tid + k * 512;
                const int row = s >> 7;
                const int c   = s & 127;
                *reinterpret_cast<unsigned long long*>(&hsd[row * 520 + c * 4]) = v[k];
            }
        }
        __syncthreads();

        // ===== phase A: att2g[:, g*32+tcol*16 ..+16] = h @ Wc^T =====
        {
            f32x4 acc = (f32x4)(0.f);
            #pragma unroll
            for (int ks = 0; ks < 16; ++ks) {
                const s16x8 af = *reinterpret_cast<const s16x8*>(
                    &hsd[(rows0 + frow) * 520 + ks * 32 + fko]);
                const s16x8 bf = *reinterpret_cast<const s16x8*>(
                    &Wc[(tcol * 16 + frow) * 520 + ks * 32 + fko]);
                acc = __builtin_amdgcn_mfma_f32_16x16x32_bf16(af, bf, acc, 0, 0, 0);
            }
            const int col = g * 32 + tcol * 16 + frow;
            #pragma unroll
            for (int r = 0; r < 4; ++r) {
                const int babs = rows0 + (lane >> 4) * 4 + r;
                astore_f(&att2g[(size_t)babs * 2048 + col], acc[r]);
            }
        }
        asm volatile("s_waitcnt vmcnt(0)" ::: "memory");
        __syncthreads();
        if (tid == 0) aset(bar + 1024 + g * 16, (unsigned)(t + 1));

        // ===== ev2: all gate cols ready =====
        if (tid < 64) {
            while (!__all((int)(apoll(bar + 1024 + tid * 16) >= (unsigned)(t + 1))))
                __builtin_amdgcn_s_sleep(1);
        }
        __syncthreads();

        // ===== gates: (g_emb + h@W_hh) + softmax-weighted featW =====
        {
            union { unsigned long long u; float f[2]; } q0, q1;
            q0.u = aload_u64(&att2g[(size_t)b * 2048 + gc]);
            q1.u = aload_u64(&att2g[(size_t)b * 2048 + gc + 2]);
            float s0 = ge.x + q0.f[0];
            float s1 = ge.y + q0.f[1];
            float s2 = ge.z + q1.f[0];
            float s3 = ge.w + q1.f[1];
            const unsigned short* fp = attFb + (size_t)(b * L_) * 2560 + 512 + gc;
            #pragma unroll 7
            for (int l = 0; l < L_; ++l) {
                const float w = wl[l];
                const s16x4 v = *reinterpret_cast<const s16x4*>(fp + (size_t)l * 2560);
                s0 = fmaf(w, b2f((unsigned short)v[0]), s0);
                s1 = fmaf(w, b2f((unsigned short)v[1]), s1);
                s2 = fmaf(w, b2f((unsigned short)v[2]), s2);
                s3 = fmaf(w, b2f((unsigned short)v[3]), s3);
            }
            *reinterpret_cast<float4*>(&gates[gc]) = make_float4(s0, s1, s2, s3);
        }
        __syncthreads();

        // ===== pointwise LSTM (c in registers; thread owns dim n=tid) =====
        {
            const float gi = gates[tid],        gf = gates[512 + tid];
            const float gg = gates[1024 + tid], go = gates[1536 + tid];
            const float i = sigmoid_fast(gi);
            const float f = sigmoid_fast(gf);
            const float gv = tanhf_fast(gg);
            const float o = sigmoid_fast(go);
            creg = f * creg + i * gv;
            hs[tid] = o * tanhf_fast(creg);
        }
        __syncthreads();

        // pack h -> bf16: coherent store to hbf, plain store to h_hist
        if (tid < 256) {
            const unsigned lo = f2b(hs[2 * tid]);
            const unsigned hi = f2b(hs[2 * tid + 1]);
            const unsigned pk = lo | (hi << 16);
            astore_u32((unsigned*)hbf + b * 256 + tid, pk);
            ((unsigned*)h_hist)[(size_t)(t * 64 + b) * 256 + tid] = pk;
        }
        asm volatile("s_waitcnt vmcnt(0)" ::: "memory");
        __syncthreads();
        if (tid == 0) aset(bar + b * 16, (unsigned)(t + 1));
    }
}

extern "C" void kernel_launch(void* const* d_in, const int* in_sizes, int n_in,
                              void* d_out, int out_size, void* d_ws, size_t ws_size,
                              hipStream_t stream)
{
    const float* features = (const float*)d_in[0];
    const int*   captions = (const int*)d_in[1];
    const float* init_h_W = (const float*)d_in[3];
    const float* init_h_b = (const float*)d_in[4];
    const float* init_c_W = (const float*)d_in[5];
    const float* init_c_b = (const float*)d_in[6];
    const float* W_a_W    = (const float*)d_in[7];
    const float* W_a_b    = (const float*)d_in[8];
    const float* U_a_W    = (const float*)d_in[9];
    const float* U_a_b    = (const float*)d_in[10];
    const float* v_a_W    = (const float*)d_in[11];
    const float* v_a_b    = (const float*)d_in[12];
    const float* embed    = (const float*)d_in[13];
    const float* W_ih     = (const float*)d_in[14];
    const float* W_hh     = (const float*)d_in[15];
    const float* b_ih     = (const float*)d_in[16];
    const float* b_hh     = (const float*)d_in[17];
    const float* fc_W     = (const float*)d_in[18];
    const float* fc_b     = (const float*)d_in[19];
    float* out = (float*)d_out;

    // ---- workspace (floats), all disjoint ----
    float* ws      = (float*)d_ws;
    float* mean_f  = ws;                                        // [0, 131072)
    float* c_st    = ws + 131072;                               // [131072, 163840)
    unsigned short* h_bf   = (unsigned short*)(ws + 163840);    // 16384 fl
    unsigned short* h_hist = (unsigned short*)(ws + 180224);    // 524288 fl
    float* att2g   = ws + 704512;                               // 131072 fl (gate part)
    unsigned short* fcW_bf = (unsigned short*)(ws + 868352);    // 3840000 fl
    unsigned* bar  = (unsigned*)(ws + 4708352);                 // 2048 uints padded
    unsigned short* uaT_bf = (unsigned short*)(ws + 4720000);   // 131072 fl -> ends 4851072

    // ---- big transients in d_out (30,720,000 fl), disjoint, dead before logits ----
    float* g_emb = out;                                              // [0, 4194304)
    unsigned short* attF_bf  = (unsigned short*)(out + 4194304);     // -> ends 8208384
    unsigned short* feat_bf  = (unsigned short*)(out + 13000000);    // -> ends 16211264
    unsigned short* wcomb_bf = (unsigned short*)(out + 17000000);    // -> ends 19621440
    unsigned short* emb_bf   = (unsigned short*)(out + 20000000);    // -> ends 20524288

    // ---- prologue ----
    k_mean<<<512, 256, 0, stream>>>(features, mean_f);

    // h0 (bf16) | c0 (f32) in ONE split-output GEMM (16 blocks — r10-proven)
    gemm64<<<dim3(1, 16), 256, 0, stream>>>(mean_f, F_DIM,
                                            init_h_W, F_DIM, H_,
                                            init_c_W, F_DIM,
                                            init_h_b, init_c_b,
                                            (float*)h_bf, H_, 2 * H_, F_DIM,
                                            2, c_st);

    // g_emb = emb @ W_ih[:, :E]^T + b_ih + b_hh  (bf16 MFMA; W cvt in-kernel)
    k_embgather<<<4096, 256, 0, stream>>>(embed, captions, emb_bf);
    gemm_mfma<<<dim3(16, 16), 256, 0, stream>>>(emb_bf, E_,
                                                W_ih, E_ + F_DIM, 4 * H_,
                                                nullptr, 0, 1,
                                                b_ih, b_hh,
                                                g_emb, 4 * H_,
                                                2048, 4 * H_, E_, 0, 0);

    // fused casts: feat_bf, wcomb_bf, fcW_bf ; U_a transpose-cast
    k_castall<<<dim3(2, 20696), 256, 0, stream>>>(features, W_a_W, W_ih, fc_W,
                                                  feat_bf, wcomb_bf, fcW_bf);
    k_castT<<<dim3(8, 8), 256, 0, stream>>>(U_a_W, uaT_bf);

    // attF(bf16) = features @ [W_a | W_ihF]^T : [3136, 2560]
    gemm_mfma<<<dim3(25, 20), 256, 0, stream>>>(feat_bf, F_DIM,
                                                wcomb_bf, 2048, 512,
                                                wcomb_bf + (size_t)512 * 2048, 2048, 0,
                                                W_a_b, nullptr,
                                                (float*)attF_bf, 2560,
                                                3136, 2560, F_DIM, 0, 1);

    // ---- recurrence: ONE persistent kernel, 64 blocks, 2 events/step ----
    hipMemsetAsync(bar, 0, 12288, stream);
    k_recur<<<NBLK_RECUR, 512, 0, stream>>>(h_bf, att2g, uaT_bf, W_hh, U_a_b,
                                            attF_bf, g_emb, v_a_W, v_a_b,
                                            c_st, h_hist, bar);

    // ---- logits: [T*B,H] @ fc_W^T + fc_b, permuted store to [B,T,V] ----
    gemm_mfma<<<dim3(16, 118), 256, 0, stream>>>(h_hist, H_,
                                                 fcW_bf, H_, V_,
                                                 nullptr, 0, 0,
                                                 fc_b, nullptr,
                                                 out, V_, 2048, V_, H_, 32, 0);
}

// Round 16
// 715.592 us; speedup vs baseline: 1.3138x; 1.3138x over previous
//
#include <hip/hip_runtime.h>
#include <math.h>

// decoderRNN: attention LSTM caption decoder, teacher-forced.
// B=64 L=49 F=2048 T=32 V=15000 E=H=A=512
#define B_ 64
#define L_ 49
#define F_DIM 2048
#define T_ 32
#define V_ 15000
#define E_ 512
#define H_ 512
#define A_ 512

typedef __attribute__((ext_vector_type(8))) short s16x8;
typedef __attribute__((ext_vector_type(4))) short s16x4;
typedef __attribute__((ext_vector_type(4))) float f32x4;

__device__ __forceinline__ unsigned short f2b(float x) {
    union { float f; unsigned int u; } v; v.f = x;
    unsigned int r = v.u + 0x7FFF + ((v.u >> 16) & 1);
    return (unsigned short)(r >> 16);
}
__device__ __forceinline__ float b2f(unsigned short u) {
    union { unsigned int i; float f; } v; v.i = ((unsigned int)u) << 16; return v.f;
}
__device__ __forceinline__ float rcp_fast(float x) {
    return __builtin_amdgcn_rcpf(x);
}
__device__ __forceinline__ float tanhf_fast(float x) {
    x = fminf(fmaxf(x, -15.f), 15.f);
    const float e = __expf(2.f * x);
    return (e - 1.f) * rcp_fast(e + 1.f);
}
__device__ __forceinline__ float sigmoid_fast(float x) {
    return rcp_fast(1.f + __expf(-x));
}

// ---- agent-scope coherent access (LLC, bypass non-coherent per-XCD L2) ----
__device__ __forceinline__ float aload_f(const float* p) {
    return __hip_atomic_load((const float*)p, __ATOMIC_RELAXED, __HIP_MEMORY_SCOPE_AGENT);
}
__device__ __forceinline__ void astore_f(float* p, float v) {
    __hip_atomic_store(p, v, __ATOMIC_RELAXED, __HIP_MEMORY_SCOPE_AGENT);
}
__device__ __forceinline__ unsigned long long aload_u64(const void* p) {
    return __hip_atomic_load((const unsigned long long*)p, __ATOMIC_RELAXED, __HIP_MEMORY_SCOPE_AGENT);
}
__device__ __forceinline__ void astore_u32(void* p, unsigned v) {
    __hip_atomic_store((unsigned*)p, v, __ATOMIC_RELAXED, __HIP_MEMORY_SCOPE_AGENT);
}
__device__ __forceinline__ unsigned apoll(const unsigned* p) {
    return __hip_atomic_load(p, __ATOMIC_RELAXED, __HIP_MEMORY_SCOPE_AGENT);
}
__device__ __forceinline__ void aset(unsigned* p, unsigned v) {
    __hip_atomic_store(p, v, __ATOMIC_RELAXED, __HIP_MEMORY_SCOPE_AGENT);
}

// ---------------- fused bf16 cast: feat | [W_a;W_ihF] | fc_W ----------------
__global__ __launch_bounds__(256)
void k_castall(const float* __restrict__ feat, const float* __restrict__ W_a,
               const float* __restrict__ W_ih, const float* __restrict__ fc_W,
               unsigned short* __restrict__ feat_bf,
               unsigned short* __restrict__ wcomb_bf,
               unsigned short* __restrict__ fcW_bf)
{
    const int r  = blockIdx.y;
    const int c4 = blockIdx.x * 256 + threadIdx.x;
    const float* src;
    unsigned short* dst;
    int cols;
    if (r < 3136)      { src = feat + (size_t)r * 2048;                 dst = feat_bf + (size_t)r * 2048;            cols = 2048; }
    else if (r < 3648) { const int rr = r - 3136; src = W_a + (size_t)rr * 2048;              dst = wcomb_bf + (size_t)rr * 2048;          cols = 2048; }
    else if (r < 5696) { const int rr = r - 3648; src = W_ih + (size_t)rr * 2560 + 512;       dst = wcomb_bf + (size_t)(rr + 512) * 2048;  cols = 2048; }
    else               { const int rr = r - 5696; src = fc_W + (size_t)rr * 512;              dst = fcW_bf + (size_t)rr * 512;             cols = 512; }
    if (c4 * 4 >= cols) return;
    float4 v = *reinterpret_cast<const float4*>(src + c4 * 4);
    ushort4 o;
    o.x = f2b(v.x); o.y = f2b(v.y); o.z = f2b(v.z); o.w = f2b(v.w);
    *reinterpret_cast<ushort4*>(dst + c4 * 4) = o;
}

// ---- bf16 MFMA GEMM: C[M,N] = A[M,K] @ W^T ----
// W rows [0,N0) from W0, [N0,N) from W1; w32!=0 -> W is f32 (cvt during stage).
// bias0 added for n<N0; bias1 added for all n.
// permT!=0: row = (m&63)*permT + (m>>6). obf!=0: store bf16.
#define LDSW 40
__global__ __launch_bounds__(256)
void gemm_mfma(const unsigned short* __restrict__ A, int lda,
               const void* __restrict__ W0p, int ldw0, int N0,
               const void* __restrict__ W1p, int ldw1, int w32,
               const float* __restrict__ bias0, const float* __restrict__ bias1,
               float* __restrict__ C, int ldc,
               int M, int N, int K, int permT, int obf)
{
    __shared__ unsigned short As[128 * LDSW];
    __shared__ unsigned short Ws[128 * LDSW];

    const int tid  = threadIdx.x;
    const int m0   = blockIdx.x * 128;
    const int n0   = blockIdx.y * 128;
    const int wave = tid >> 6;
    const int lane = tid & 63;
    const int wr   = (wave >> 1) * 64;
    const int wc   = (wave & 1) * 64;

    f32x4 acc[4][4];
    #pragma unroll
    for (int i = 0; i < 4; ++i)
        #pragma unroll
        for (int j = 0; j < 4; ++j)
            acc[i][j] = (f32x4)(0.f);

    const int fr = lane & 15;
    const int fk = (lane >> 4) * 8;

    for (int kc = 0; kc < K; kc += 32) {
        ushort4 av[2][2], wv[2][2];
        #pragma unroll
        for (int i = 0; i < 2; ++i) {
            const int idx = tid + i * 256;
            const int row = idx >> 2;
            const int seg = idx & 3;
            av[i][0] = make_ushort4(0, 0, 0, 0); av[i][1] = make_ushort4(0, 0, 0, 0);
            wv[i][0] = make_ushort4(0, 0, 0, 0); wv[i][1] = make_ushort4(0, 0, 0, 0);
            if (m0 + row < M) {
                const float4 t0 = *reinterpret_cast<const float4*>(
                    A + (size_t)(m0 + row) * lda + kc + seg * 8);
                *reinterpret_cast<float4*>(&av[i][0]) = t0;
            }
            const int n_abs = n0 + row;
            if (n_abs < N) {
                if (w32) {
                    const float* wrow = (n_abs < N0)
                        ? ((const float*)W0p + (size_t)n_abs * ldw0)
                        : ((const float*)W1p + (size_t)(n_abs - N0) * ldw1);
                    const float4 x = *reinterpret_cast<const float4*>(wrow + kc + seg * 8);
                    const float4 y = *reinterpret_cast<const float4*>(wrow + kc + seg * 8 + 4);
                    wv[i][0] = make_ushort4(f2b(x.x), f2b(x.y), f2b(x.z), f2b(x.w));
                    wv[i][1] = make_ushort4(f2b(y.x), f2b(y.y), f2b(y.z), f2b(y.w));
                } else {
                    const unsigned short* wrow = (n_abs < N0)
                        ? ((const unsigned short*)W0p + (size_t)n_abs * ldw0)
                        : ((const unsigned short*)W1p + (size_t)(n_abs - N0) * ldw1);
                    const float4 t0 = *reinterpret_cast<const float4*>(wrow + kc + seg * 8);
                    *reinterpret_cast<float4*>(&wv[i][0]) = t0;
                }
            }
        }
        __syncthreads();
        #pragma unroll
        for (int i = 0; i < 2; ++i) {
            const int idx = tid + i * 256;
            const int row = idx >> 2;
            const int seg = idx & 3;
            *reinterpret_cast<ushort4*>(&As[row * LDSW + seg * 8])     = av[i][0];
            *reinterpret_cast<ushort4*>(&As[row * LDSW + seg * 8 + 4]) = av[i][1];
            *reinterpret_cast<ushort4*>(&Ws[row * LDSW + seg * 8])     = wv[i][0];
            *reinterpret_cast<ushort4*>(&Ws[row * LDSW + seg * 8 + 4]) = wv[i][1];
        }
        __syncthreads();

        s16x8 afr[4], bfr[4];
        #pragma unroll
        for (int mf = 0; mf < 4; ++mf)
            afr[mf] = *reinterpret_cast<const s16x8*>(&As[(wr + mf * 16 + fr) * LDSW + fk]);
        #pragma unroll
        for (int nf = 0; nf < 4; ++nf)
            bfr[nf] = *reinterpret_cast<const s16x8*>(&Ws[(wc + nf * 16 + fr) * LDSW + fk]);

        #pragma unroll
        for (int mf = 0; mf < 4; ++mf)
            #pragma unroll
            for (int nf = 0; nf < 4; ++nf)
                acc[mf][nf] = __builtin_amdgcn_mfma_f32_16x16x32_bf16(
                    afr[mf], bfr[nf], acc[mf][nf], 0, 0, 0);
    }

    const int cr = (lane >> 4) * 4;
    const int cc = lane & 15;
    #pragma unroll
    for (int nf = 0; nf < 4; ++nf) {
        const int n = n0 + wc + nf * 16 + cc;
        if (n >= N) continue;
        float bv = 0.f;
        if (bias0 && n < N0) bv += bias0[n];
        if (bias1) bv += bias1[n];
        #pragma unroll
        for (int mf = 0; mf < 4; ++mf) {
            #pragma unroll
            for (int r = 0; r < 4; ++r) {
                const int m = m0 + wr + mf * 16 + cr + r;
                if (m >= M) continue;
                const size_t row = permT ? ((size_t)(m & 63) * permT + (size_t)(m >> 6))
                                         : (size_t)m;
                const float v = acc[mf][nf][r] + bv;
                if (obf) ((unsigned short*)C)[row * (size_t)ldc + n] = f2b(v);
                else     C[row * (size_t)ldc + n] = v;
            }
        }
    }
}

// ---------------- generic tiled f32 GEMM (tiny prologue matmuls) ----------------
// obf: 0=f32->C ; 1=bf16->C ; 2=split (n<N0 bf16->C ld N0, n>=N0 f32->C2 ld N-N0)
__global__ __launch_bounds__(256)
void gemm64(const float* __restrict__ A, int lda,
            const float* __restrict__ W0, int ldw0, int N0,
            const float* __restrict__ W1, int ldw1,
            const float* __restrict__ bias0, const float* __restrict__ bias1,
            float* __restrict__ C, int ldc,
            int N, int K, int obf, float* __restrict__ C2)
{
    __shared__ float As[16][64];
    __shared__ float Ws[16][64];

    const int tid = threadIdx.x;
    const int m0  = blockIdx.x * 64;
    const int n0  = blockIdx.y * 64;

    const int lr = tid >> 2;
    const int kq = tid & 3;

    const int n_abs = n0 + lr;
    const bool wvalid = (n_abs < N);
    const float* wrow = nullptr;
    if (wvalid)
        wrow = (n_abs < N0) ? (W0 + (size_t)n_abs * ldw0)
                            : (W1 + (size_t)(n_abs - N0) * ldw1);
    const float* arow = A + (size_t)(m0 + lr) * lda;

    const int ty = tid >> 4;
    const int tx = tid & 15;

    float acc[4][4] = {{0.f}};

    for (int kc = 0; kc < K; kc += 16) {
        float4 av = *reinterpret_cast<const float4*>(arow + kc + kq * 4);
        float4 wv = make_float4(0.f, 0.f, 0.f, 0.f);
        if (wvalid)
            wv = *reinterpret_cast<const float4*>(wrow + kc + kq * 4);

        __syncthreads();
        As[kq * 4 + 0][lr] = av.x;
        As[kq * 4 + 1][lr] = av.y;
        As[kq * 4 + 2][lr] = av.z;
        As[kq * 4 + 3][lr] = av.w;
        Ws[kq * 4 + 0][lr] = wv.x;
        Ws[kq * 4 + 1][lr] = wv.y;
        Ws[kq * 4 + 2][lr] = wv.z;
        Ws[kq * 4 + 3][lr] = wv.w;
        __syncthreads();

        #pragma unroll
        for (int kk = 0; kk < 16; ++kk) {
            const float4 a4 = *reinterpret_cast<const float4*>(&As[kk][ty * 4]);
            const float4 w4 = *reinterpret_cast<const float4*>(&Ws[kk][tx * 4]);
            const float aa[4] = {a4.x, a4.y, a4.z, a4.w};
            const float ww[4] = {w4.x, w4.y, w4.z, w4.w};
            #pragma unroll
            for (int i = 0; i < 4; ++i)
                #pragma unroll
                for (int j = 0; j < 4; ++j)
                    acc[i][j] = fmaf(aa[i], ww[j], acc[i][j]);
        }
    }

    #pragma unroll
    for (int i = 0; i < 4; ++i) {
        const int m = m0 + ty * 4 + i;
        #pragma unroll
        for (int j = 0; j < 4; ++j) {
            const int n = n0 + tx * 4 + j;
            if (n >= N) continue;
            float v = acc[i][j];
            if (bias0 && n < N0) v += bias0[n];
            if (bias1 && n >= N0) v += bias1[n - N0];
            if (obf == 2) {
                if (n < N0) ((unsigned short*)C)[(size_t)m * N0 + n] = f2b(v);
                else        C2[(size_t)m * (N - N0) + (n - N0)] = v;
            } else if (obf == 1) {
                ((unsigned short*)C)[(size_t)m * ldc + n] = f2b(v);
            } else {
                C[(size_t)m * ldc + n] = v;
            }
        }
    }
}

// ---------------- mean over L (f32 out, feeds gemm64) ----------------
__global__ __launch_bounds__(256)
void k_mean(const float* __restrict__ feat, float* __restrict__ mean_f)
{
    const int idx = blockIdx.x * 256 + threadIdx.x;
    const int b = idx >> 11;
    const int f = idx & 2047;
    const float* p = feat + (size_t)b * L_ * F_DIM + f;
    float s = 0.f;
    #pragma unroll 7
    for (int l = 0; l < L_; ++l) s += p[(size_t)l * F_DIM];
    mean_f[idx] = s * (1.0f / 49.0f);
}

// ---------------- embedding gather (bf16 out) ----------------
__global__ __launch_bounds__(256)
void k_embgather(const float* __restrict__ table, const int* __restrict__ caps,
                 unsigned short* __restrict__ emb_bf)
{
    const int idx = blockIdx.x * 256 + threadIdx.x;
    const int e   = idx & 511;
    const int row = idx >> 9;
    const int t   = row >> 6;
    const int b   = row & 63;
    const int tok = caps[b * T_ + t];
    emb_bf[idx] = f2b(table[(size_t)tok * E_ + e]);
}

// ---------------- persistent recurrence kernel (r14-proven, unchanged) ----------------
// 80 blocks x 512 thr, NO pump. Arrivals: each block plain-stores generation
// into its OWN 64B-padded slot (no RMW). Consumers poll producer slots
// DIRECTLY with one wave (lane i <-> slot i, __all). 3 events/step.
// Phase A stages h via bulk parallel agent loads -> LDS, MFMAs from LDS.
// Phase B prefetches IMMUTABLE operands (attFb score rows, g_emb) before any
// wait; the consume loop is a FIXED 7-iteration #pragma unroll (rule #20 —
// runtime-indexed reg arrays go to scratch: r12 regression 446->1771 us).
#define NBLK_RECUR 80u
// bar (uints, 16-uint padded): [i*16] slotB(i<64) ; [1024+i*16] slotA16(i<16) ;
//                              [1280+i*16] slotA(i<80)

__global__ __launch_bounds__(512)
void k_recur(unsigned short* __restrict__ hbf,      // [64][512] bf16 (coherent)
             float* __restrict__ att2g,             // [64][2560] (coherent)
             const float* __restrict__ U_a,         // [512][512]
             const float* __restrict__ W_hh,        // [2048][512]
             const float* __restrict__ U_a_b,       // [512]
             const unsigned short* __restrict__ attFb, // [3136][2560] bf16
             const float* __restrict__ g_emb,       // [32][64][2048]
             const float* __restrict__ v_w, const float* __restrict__ v_b,
             const float* __restrict__ c0,          // [64][512] initial c
             unsigned short* __restrict__ h_hist,   // [32][64][512] bf16
             unsigned* __restrict__ bar)
{
    const int g   = blockIdx.x;
    const int tid = threadIdx.x;

    __shared__ unsigned short Wc[32 * 520];    // 32 weight rows (bf16)
    __shared__ unsigned short hsd[64 * 520];   // staged h (bf16, padded)
    __shared__ float a2[512];
    __shared__ float wl[64];
    __shared__ float gates[2048];
    __shared__ float hs[512];
    __shared__ float vws[512];
    __shared__ float vub[512];

    const int R    = g * 32;
    const int wave = tid >> 6;
    const int lane = tid & 63;

    // one-time: 32 weight rows f32 -> bf16 LDS; v_w; U_a_b
    for (int idx = tid; idx < 4096; idx += 512) {   // 32 rows x 128 float4
        const int r  = idx >> 7;
        const int kq = idx & 127;
        const int n  = R + r;
        const float* src = (n < 512) ? (U_a + (size_t)n * 512)
                                     : (W_hh + (size_t)(n - 512) * 512);
        float4 v = *reinterpret_cast<const float4*>(src + kq * 4);
        unsigned short* d = &Wc[r * 520 + kq * 4];
        d[0] = f2b(v.x); d[1] = f2b(v.y); d[2] = f2b(v.z); d[3] = f2b(v.w);
    }
    vws[tid] = v_w[tid];
    vub[tid] = U_a_b[tid];

    const int isB = (g < 64);
    const int b   = g;
    const float vb0 = v_b[0];

    // phase-B constants + register cell state (thread owns LSTM dim n=tid)
    const int ggrp = tid >> 7;          // gate group i/f/g/o
    const int jj   = (tid & 127) * 4;
    const int gc   = ggrp * 512 + jj;
    float creg = 0.f;
    if (isB) creg = c0[b * 512 + tid];

    // phase-A constants
    const int tcol  = wave >> 2;        // 0/1: which 16-col tile
    const int rows0 = (wave & 3) * 16;  // h-row base
    const int frow  = lane & 15;
    const int fko   = (lane >> 4) * 8;
    __syncthreads();

    for (int t = 0; t < T_; ++t) {
        // ===== wait: h(t) ready (poll all 64 B slots directly) =====
        if (t > 0) {
            if (tid < 64) {
                while (!__all((int)(apoll(bar + tid * 16) >= (unsigned)t)))
                    __builtin_amdgcn_s_sleep(1);
            }
            __syncthreads();
        }

        // ===== stage h -> LDS: 16 independent u64 loads/thread, then store ===
        {
            unsigned long long v[16];
            #pragma unroll
            for (int k = 0; k < 16; ++k)
                v[k] = aload_u64((const unsigned char*)hbf + ((size_t)(tid + k * 512)) * 8);
            #pragma unroll
            for (int k = 0; k < 16; ++k) {
                const int s   = tid + k * 512;   // u64 slot: 128 per row
                const int row = s >> 7;
                const int c   = s & 127;
                *reinterpret_cast<unsigned long long*>(&hsd[row * 520 + c * 4]) = v[k];
            }
        }
        __syncthreads();

        // ===== phase A: att2g[:, R+tcol*16 ..+16] = h @ Wc^T (from LDS) =====
        {
            f32x4 acc = (f32x4)(0.f);
            #pragma unroll
            for (int ks = 0; ks < 16; ++ks) {
                const s16x8 af = *reinterpret_cast<const s16x8*>(
                    &hsd[(rows0 + frow) * 520 + ks * 32 + fko]);
                const s16x8 bf = *reinterpret_cast<const s16x8*>(
                    &Wc[(tcol * 16 + frow) * 520 + ks * 32 + fko]);
                acc = __builtin_amdgcn_mfma_f32_16x16x32_bf16(af, bf, acc, 0, 0, 0);
            }
            const int col = R + tcol * 16 + frow;
            #pragma unroll
            for (int r = 0; r < 4; ++r) {
                const int babs = rows0 + (lane >> 4) * 4 + r;
                astore_f(&att2g[(size_t)babs * 2560 + col], acc[r]);
            }
        }
        asm volatile("s_waitcnt vmcnt(0)" ::: "memory");
        __syncthreads();
        if (tid == 0) {
            if (g < 16) aset(bar + 1024 + g * 16, (unsigned)(t + 1));   // att cols done
            aset(bar + 1280 + g * 16, (unsigned)(t + 1));               // full slice done
        }

        // ===== phase B (blocks 0..63) =====
        if (isB) {
            // prefetch IMMUTABLE operands before any wait (no writer -> race-free)
            s16x8 a1pf[7];
            #pragma unroll
            for (int i = 0; i < 7; ++i) {
                int l = wave + i * 8; if (l > 48) l = 48;   // clamped; unused if OOB
                a1pf[i] = *reinterpret_cast<const s16x8*>(
                    attFb + (size_t)(b * L_ + l) * 2560 + lane * 8);
            }
            const float4 ge = *reinterpret_cast<const float4*>(
                g_emb + ((size_t)t * 64 + b) * 2048 + gc);

            // wait: att cols (slots A16[0..15]) ready
            if (tid < 64) {
                while (!__all((int)(tid >= 16 ||
                        apoll(bar + 1024 + tid * 16) >= (unsigned)(t + 1))))
                    __builtin_amdgcn_s_sleep(1);
            }
            __syncthreads();

            a2[tid] = aload_f(&att2g[(size_t)b * 2560 + tid]) + vub[tid];
            __syncthreads();

            // scores over L=49: FIXED trip count, compile-time a1pf index
            #pragma unroll
            for (int i = 0; i < 7; ++i) {
                const int l = wave + i * 8;      // wave-uniform
                if (l < L_) {
                    float s = 0.f;
                    #pragma unroll
                    for (int j = 0; j < 8; ++j)
                        s += tanhf_fast(b2f((unsigned short)a1pf[i][j]) + a2[lane * 8 + j]) * vws[lane * 8 + j];
                    #pragma unroll
                    for (int off = 32; off > 0; off >>= 1) s += __shfl_down(s, off);
                    if (lane == 0) wl[l] = s + vb0;
                }
            }
            __syncthreads();

            if (tid < 64) {
                float v = (tid < L_) ? wl[tid] : -3.0e38f;
                float mx = v;
                #pragma unroll
                for (int off = 32; off > 0; off >>= 1) mx = fmaxf(mx, __shfl_xor(mx, off));
                float e = (tid < L_) ? __expf(v - mx) : 0.f;
                float sum = e;
                #pragma unroll
                for (int off = 32; off > 0; off >>= 1) sum += __shfl_xor(sum, off);
                if (tid < L_) wl[tid] = e * rcp_fast(sum);
            }

            // wait: full att2g (all 80 A slots) — overlaps with scores above
            if (tid < 64) {
                for (;;) {
                    const unsigned v0 = apoll(bar + 1280 + tid * 16);
                    const unsigned v1 = (tid < 16) ? apoll(bar + 1280 + (tid + 64) * 16)
                                                   : 0xFFFFFFFFu;
                    if (__all((int)(v0 >= (unsigned)(t + 1) && v1 >= (unsigned)(t + 1)))) break;
                    __builtin_amdgcn_s_sleep(1);
                }
            }
            __syncthreads();

            // gates: (g_emb + h@W_hh) + softmax-weighted featW
            {
                union { unsigned long long u; float f[2]; } q0, q1;
                q0.u = aload_u64(&att2g[(size_t)b * 2560 + 512 + gc]);
                q1.u = aload_u64(&att2g[(size_t)b * 2560 + 512 + gc + 2]);
                float s0 = ge.x + q0.f[0];
                float s1 = ge.y + q0.f[1];
                float s2 = ge.z + q1.f[0];
                float s3 = ge.w + q1.f[1];
                const unsigned short* fp = attFb + (size_t)(b * L_) * 2560 + 512 + gc;
                #pragma unroll 7
                for (int l = 0; l < L_; ++l) {
                    const float w = wl[l];
                    const s16x4 v = *reinterpret_cast<const s16x4*>(fp + (size_t)l * 2560);
                    s0 = fmaf(w, b2f((unsigned short)v[0]), s0);
                    s1 = fmaf(w, b2f((unsigned short)v[1]), s1);
                    s2 = fmaf(w, b2f((unsigned short)v[2]), s2);
                    s3 = fmaf(w, b2f((unsigned short)v[3]), s3);
                }
                *reinterpret_cast<float4*>(&gates[gc]) = make_float4(s0, s1, s2, s3);
            }
            __syncthreads();

            // pointwise LSTM (c in registers; thread owns dim n=tid)
            {
                const float gi = gates[tid],        gf = gates[512 + tid];
                const float gg = gates[1024 + tid], go = gates[1536 + tid];
                const float i = sigmoid_fast(gi);
                const float f = sigmoid_fast(gf);
                const float gv = tanhf_fast(gg);
                const float o = sigmoid_fast(go);
                creg = f * creg + i * gv;
                hs[tid] = o * tanhf_fast(creg);
            }
            __syncthreads();

            // pack h -> bf16: coherent store to hbf, plain store to h_hist
            if (tid < 256) {
                const unsigned lo = f2b(hs[2 * tid]);
                const unsigned hi = f2b(hs[2 * tid + 1]);
                const unsigned pk = lo | (hi << 16);
                astore_u32((unsigned*)hbf + b * 256 + tid, pk);
                ((unsigned*)h_hist)[(size_t)(t * 64 + b) * 256 + tid] = pk;
            }
            asm volatile("s_waitcnt vmcnt(0)" ::: "memory");
            __syncthreads();
            if (tid == 0) aset(bar + b * 16, (unsigned)(t + 1));
        }
    }
}

extern "C" void kernel_launch(void* const* d_in, const int* in_sizes, int n_in,
                              void* d_out, int out_size, void* d_ws, size_t ws_size,
                              hipStream_t stream)
{
    const float* features = (const float*)d_in[0];
    const int*   captions = (const int*)d_in[1];
    const float* init_h_W = (const float*)d_in[3];
    const float* init_h_b = (const float*)d_in[4];
    const float* init_c_W = (const float*)d_in[5];
    const float* init_c_b = (const float*)d_in[6];
    const float* W_a_W    = (const float*)d_in[7];
    const float* W_a_b    = (const float*)d_in[8];
    const float* U_a_W    = (const float*)d_in[9];
    const float* U_a_b    = (const float*)d_in[10];
    const float* v_a_W    = (const float*)d_in[11];
    const float* v_a_b    = (const float*)d_in[12];
    const float* embed    = (const float*)d_in[13];
    const float* W_ih     = (const float*)d_in[14];
    const float* W_hh     = (const float*)d_in[15];
    const float* b_ih     = (const float*)d_in[16];
    const float* b_hh     = (const float*)d_in[17];
    const float* fc_W     = (const float*)d_in[18];
    const float* fc_b     = (const float*)d_in[19];
    float* out = (float*)d_out;

    // ---- workspace (floats), all disjoint ----
    float* ws      = (float*)d_ws;
    float* mean_f  = ws;                                        // [0, 131072)
    float* c_st    = ws + 131072;                               // [131072, 163840)
    unsigned short* h_bf   = (unsigned short*)(ws + 163840);    // 16384 fl
    unsigned short* h_hist = (unsigned short*)(ws + 180224);    // 524288 fl
    float* att2g   = ws + 704512;                               // 163840 fl
    unsigned short* fcW_bf = (unsigned short*)(ws + 868352);    // 3840000 fl
    unsigned* bar  = (unsigned*)(ws + 4708352);                 // 2560 uints padded

    // ---- big transients in d_out (30,720,000 fl), disjoint, dead before logits ----
    float* g_emb = out;                                              // [0, 4194304)
    unsigned short* attF_bf  = (unsigned short*)(out + 4194304);     // -> ends 8208384
    unsigned short* feat_bf  = (unsigned short*)(out + 13000000);    // -> ends 16211264
    unsigned short* wcomb_bf = (unsigned short*)(out + 17000000);    // -> ends 19621440
    unsigned short* emb_bf   = (unsigned short*)(out + 20000000);    // -> ends 20524288

    // ---- prologue ----
    k_mean<<<512, 256, 0, stream>>>(features, mean_f);

    // h0 (bf16) | c0 (f32) in ONE split-output GEMM (16 blocks — r10-proven)
    gemm64<<<dim3(1, 16), 256, 0, stream>>>(mean_f, F_DIM,
                                            init_h_W, F_DIM, H_,
                                            init_c_W, F_DIM,
                                            init_h_b, init_c_b,
                                            (float*)h_bf, H_, 2 * H_, F_DIM,
                                            2, c_st);

    // g_emb = emb @ W_ih[:, :E]^T + b_ih + b_hh  (bf16 MFMA; W cvt in-kernel)
    k_embgather<<<4096, 256, 0, stream>>>(embed, captions, emb_bf);
    gemm_mfma<<<dim3(16, 16), 256, 0, stream>>>(emb_bf, E_,
                                                W_ih, E_ + F_DIM, 4 * H_,
                                                nullptr, 0, 1,
                                                b_ih, b_hh,
                                                g_emb, 4 * H_,
                                                2048, 4 * H_, E_, 0, 0);

    // fused casts: feat_bf, wcomb_bf, fcW_bf
    k_castall<<<dim3(2, 20696), 256, 0, stream>>>(features, W_a_W, W_ih, fc_W,
                                                  feat_bf, wcomb_bf, fcW_bf);

    // attF(bf16) = features @ [W_a | W_ihF]^T : [3136, 2560]
    gemm_mfma<<<dim3(25, 20), 256, 0, stream>>>(feat_bf, F_DIM,
                                                wcomb_bf, 2048, 512,
                                                wcomb_bf + (size_t)512 * 2048, 2048, 0,
                                                W_a_b, nullptr,
                                                (float*)attF_bf, 2560,
                                                3136, 2560, F_DIM, 0, 1);

    // ---- recurrence: ONE persistent kernel, direct slot-poll sync ----
    hipMemsetAsync(bar, 0, 12288, stream);
    k_recur<<<NBLK_RECUR, 512, 0, stream>>>(h_bf, att2g, U_a_W, W_hh, U_a_b,
                                            attF_bf, g_emb, v_a_W, v_a_b,
                                            c_st, h_hist, bar);

    // ---- logits: [T*B,H] @ fc_W^T + fc_b, permuted store to [B,T,V] ----
    gemm_mfma<<<dim3(16, 118), 256, 0, stream>>>(h_hist, H_,
                                                 fcW_bf, H_, V_,
                                                 nullptr, 0, 0,
                                                 fc_b, nullptr,
                                                 out, V_, 2048, V_, H_, 32, 0);
}